// Round 9
// baseline (662.201 us; speedup 1.0000x reference)
//
#include <hip/hip_runtime.h>
#include <hip/hip_bf16.h>
#include <math.h>

#define CAP 2048
#define PRNG_PARTITIONABLE 1

typedef __attribute__((ext_vector_type(8))) short bf16x8;
typedef __attribute__((ext_vector_type(4))) float f32x4;
typedef __attribute__((ext_vector_type(4))) unsigned int u32x4;

union B8U4 { u32x4 u; bf16x8 b; };

// ---------- helpers ----------
__device__ __forceinline__ unsigned int f2ord(float x) {
  unsigned int u = __float_as_uint(x);
  return (u & 0x80000000u) ? ~u : (u | 0x80000000u);
}

__device__ __forceinline__ unsigned int rotl_u32(unsigned int x, int r) {
  return (x << r) | (x >> (32 - r));
}

__device__ float gumbel_at(unsigned int flat, unsigned int half_n) {
  const unsigned int ks0 = 0u;
  const unsigned int ks1 = 42u;
  const unsigned int ks2 = 0x1BD11BDAu ^ ks0 ^ ks1;
  unsigned int x0, x1;
#if PRNG_PARTITIONABLE
  x0 = 0u;
  x1 = flat;
#else
  unsigned int cnt = (flat < half_n) ? flat : (flat - half_n);
  x0 = cnt; x1 = cnt + half_n;
#endif
  x0 += ks0; x1 += ks1;
#define TF_R(r) { x0 += x1; x1 = rotl_u32(x1, r); x1 ^= x0; }
  TF_R(13) TF_R(15) TF_R(26) TF_R(6)
  x0 += ks1; x1 += ks2 + 1u;
  TF_R(17) TF_R(29) TF_R(16) TF_R(24)
  x0 += ks2; x1 += ks0 + 2u;
  TF_R(13) TF_R(15) TF_R(26) TF_R(6)
  x0 += ks0; x1 += ks1 + 3u;
  TF_R(17) TF_R(29) TF_R(16) TF_R(24)
  x0 += ks1; x1 += ks2 + 4u;
  TF_R(13) TF_R(15) TF_R(26) TF_R(6)
  x0 += ks2; x1 += ks0 + 5u;
#undef TF_R
#if PRNG_PARTITIONABLE
  unsigned int bits = x0 ^ x1;
#else
  unsigned int bits = (flat < half_n) ? x0 : x1;
#endif
  float f = __uint_as_float(0x3f800000u | (bits >> 9)) - 1.0f;
  float u = fmaxf(1e-20f, f + 1e-20f);
  return -logf(-logf(u));
}

__device__ __forceinline__ unsigned short f32_to_bf16_rne(float x) {
  unsigned int u = __float_as_uint(x);
  unsigned int r = u + 0x7fffu + ((u >> 16) & 1u);
  return (unsigned short)(r >> 16);
}
__device__ __forceinline__ float bf16u_to_f32(unsigned short h) {
  return __uint_as_float(((unsigned int)h) << 16);
}

struct HL { unsigned int h, l; };
__device__ __forceinline__ HL cvt_pair(float a, float b) {
  float2 xf = make_float2(a, b);
  __hip_bfloat162 hh = __float22bfloat162_rn(xf);
  float2 hf = __bfloat1622float2(hh);
  __hip_bfloat162 ll = __float22bfloat162_rn(make_float2(a - hf.x, b - hf.y));
  HL r;
  __builtin_memcpy(&r.h, &hh, 4);
  __builtin_memcpy(&r.l, &ll, 4);
  return r;
}

__device__ __forceinline__ f32x4 mfma16(bf16x8 a, bf16x8 b, f32x4 c) {
  return __builtin_amdgcn_mfma_f32_16x16x32_bf16(a, b, c, 0, 0, 0);
}

// ---------- K0: gather last-token rows + split to bf16 hi/lo ----------
__global__ void gather_split(const float* __restrict__ hidden, const int* __restrict__ lti,
                             unsigned short* __restrict__ Ah, unsigned short* __restrict__ Al,
                             int D) {
  int b = blockIdx.x;
  const float* src = hidden + (size_t)lti[b] * D;
  for (int i = threadIdx.x; i < D; i += blockDim.x) {
    float x = src[i];
    unsigned short h = f32_to_bf16_rne(x);
    float r = x - bf16u_to_f32(h);
    Ah[(size_t)b * D + i] = h;
    Al[(size_t)b * D + i] = f32_to_bf16_rne(r);
  }
}

// ---------- K1: logits = A @ E^T via bf16x3 MFMA ----------
// BM=64, BN=128, BK=64. 4 waves; wave w owns n in [w*32, w*32+32).
// B stored as raw f32 in LDS (convert-on-read, under MFMA shadow).
// B swizzle: 16B grans (4 f32), 16/row, phys_gran = g ^ (n&7).
// A bf16 hi/lo LDS: 16B grans (8 bf16), 8/row, phys_gran = g ^ (r&7).
#define BN 128
#define BK 64
__global__ __launch_bounds__(256) void gemm_mfma(
    const unsigned short* __restrict__ Ahg, const unsigned short* __restrict__ Alg,
    const float* __restrict__ E, float* __restrict__ outL, int D, int V) {
  __shared__ __align__(16) float BS[128 * 64];
  __shared__ __align__(16) unsigned short AhS[64 * 64];
  __shared__ __align__(16) unsigned short AlS[64 * 64];

  const int t = threadIdx.x;
  const int lane = t & 63;
  const int wv = t >> 6;
  const long n0 = (long)blockIdx.x * BN;
  const int am = t >> 2, ao = t & 3;  // A staging: row am, 16-elem group ao

  f32x4 acc[4][2];
#pragma unroll
  for (int i = 0; i < 4; ++i)
#pragma unroll
    for (int j = 0; j < 2; ++j) acc[i][j] = (f32x4){0.f, 0.f, 0.f, 0.f};

  f32x4 bA[8], bB[8];
  bf16x8 aA[4], aB[4];

  auto LOAD = [&](f32x4* br, bf16x8* ar, int k0) {
#pragma unroll
    for (int q = 0; q < 4; ++q) {
      int gi = q * 256 + t, n = gi >> 3, o = gi & 7;
      const float* s = E + (size_t)(n0 + n) * D + k0 + o * 8;
      br[2 * q] = *(const f32x4*)s;
      br[2 * q + 1] = *(const f32x4*)(s + 4);
    }
    const unsigned short* ph = Ahg + (size_t)am * D + k0 + ao * 16;
    ar[0] = *(const bf16x8*)ph;
    ar[1] = *(const bf16x8*)(ph + 8);
    const unsigned short* pl = Alg + (size_t)am * D + k0 + ao * 16;
    ar[2] = *(const bf16x8*)pl;
    ar[3] = *(const bf16x8*)(pl + 8);
  };

  auto STAGE = [&](f32x4* br, bf16x8* ar) {
#pragma unroll
    for (int q = 0; q < 4; ++q) {
      int gi = q * 256 + t, n = gi >> 3, o = gi & 7;
      int pg0 = (2 * o) ^ (n & 7);
      int pg1 = (2 * o + 1) ^ (n & 7);
      *(f32x4*)&BS[n * 64 + pg0 * 4] = br[2 * q];
      *(f32x4*)&BS[n * 64 + pg1 * 4] = br[2 * q + 1];
    }
    int g0 = ao * 2;
    int off0 = am * 64 + ((g0 ^ (am & 7)) * 8);
    int off1 = am * 64 + (((g0 + 1) ^ (am & 7)) * 8);
    *(bf16x8*)&AhS[off0] = ar[0];
    *(bf16x8*)&AhS[off1] = ar[1];
    *(bf16x8*)&AlS[off0] = ar[2];
    *(bf16x8*)&AlS[off1] = ar[3];
  };

  auto COMPUTE = [&]() {
#pragma unroll
    for (int k32 = 0; k32 < 2; ++k32) {
      const int og = k32 * 4 + (lane >> 4);
      bf16x8 ah[4], al[4], bh[2], bl[2];
#pragma unroll
      for (int mf = 0; mf < 4; ++mf) {
        int r = mf * 16 + (lane & 15);
        int off = r * 64 + ((og ^ (r & 7)) * 8);
        ah[mf] = *(const bf16x8*)&AhS[off];
        al[mf] = *(const bf16x8*)&AlS[off];
      }
#pragma unroll
      for (int nf = 0; nf < 2; ++nf) {
        int n = wv * 32 + nf * 16 + (lane & 15);
        int pg0 = (2 * og) ^ (n & 7);
        int pg1 = (2 * og + 1) ^ (n & 7);
        f32x4 v0 = *(const f32x4*)&BS[n * 64 + pg0 * 4];
        f32x4 v1 = *(const f32x4*)&BS[n * 64 + pg1 * 4];
        HL p0 = cvt_pair(v0.x, v0.y);
        HL p1 = cvt_pair(v0.z, v0.w);
        HL p2 = cvt_pair(v1.x, v1.y);
        HL p3 = cvt_pair(v1.z, v1.w);
        B8U4 hb, lb;
        hb.u = (u32x4){p0.h, p1.h, p2.h, p3.h};
        lb.u = (u32x4){p0.l, p1.l, p2.l, p3.l};
        bh[nf] = hb.b;
        bl[nf] = lb.b;
      }
      __builtin_amdgcn_s_setprio(1);
#pragma unroll
      for (int mf = 0; mf < 4; ++mf)
#pragma unroll
        for (int nf = 0; nf < 2; ++nf) {
          acc[mf][nf] = mfma16(ah[mf], bh[nf], acc[mf][nf]);
          acc[mf][nf] = mfma16(ah[mf], bl[nf], acc[mf][nf]);
          acc[mf][nf] = mfma16(al[mf], bh[nf], acc[mf][nf]);
        }
      __builtin_amdgcn_s_setprio(0);
    }
  };

  LOAD(bA, aA, 0);
#pragma unroll 1
  for (int k0 = 0; k0 < D; k0 += 2 * BK) {
    if (k0 + BK < D) LOAD(bB, aB, k0 + BK);          // issue-early: tile k+1
    __syncthreads();
    STAGE(bA, aA);
    __syncthreads();
    COMPUTE();
    if (k0 + 2 * BK < D) LOAD(bA, aA, k0 + 2 * BK);  // issue-early: tile k+2
    __syncthreads();
    STAGE(bB, aB);
    __syncthreads();
    COMPUTE();
  }

  // epilogue: D layout col=lane&15, row=(lane>>4)*4+reg
#pragma unroll
  for (int mf = 0; mf < 4; ++mf)
#pragma unroll
    for (int nf = 0; nf < 2; ++nf) {
      long v = n0 + wv * 32 + nf * 16 + (lane & 15);
      int rbase = mf * 16 + ((lane >> 4) << 2);
#pragma unroll
      for (int reg = 0; reg < 4; ++reg)
        outL[(size_t)(rbase + reg) * V + v] = acc[mf][nf][reg];
    }
}

// ---------- K2: candidate select, 16-bit two-level threshold ----------
__global__ __launch_bounds__(1024) void select_topk(
    const float* __restrict__ logits, const int* __restrict__ top_ks,
    float* __restrict__ cvals, int* __restrict__ cidx, int* __restrict__ ccnt, int V) {
  const int b = blockIdx.x;
  const float* row = logits + (size_t)b * V;
  const int tid = threadIdx.x;
  const int wv = tid >> 6;
  __shared__ unsigned int hist[16][256];
  __shared__ int s_bin, s_cntGT, s_refine;
  __shared__ unsigned int s_tau;
  __shared__ int s_cnt;

  int k = top_ks[b];
  if (k < 1) k = 1;
  if (k > V) k = V;

  for (int i = tid; i < 16 * 256; i += 1024) ((unsigned int*)hist)[i] = 0u;
  __syncthreads();

  // pass 1: top-byte histogram (f32x4 vectorized)
  for (int i = tid * 4; i < V; i += 4096) {
    f32x4 v4 = *(const f32x4*)(row + i);
    atomicAdd(&hist[wv][f2ord(v4.x) >> 24], 1u);
    atomicAdd(&hist[wv][f2ord(v4.y) >> 24], 1u);
    atomicAdd(&hist[wv][f2ord(v4.z) >> 24], 1u);
    atomicAdd(&hist[wv][f2ord(v4.w) >> 24], 1u);
  }
  __syncthreads();
  if (tid < 256) {
    unsigned int s = 0;
    for (int w = 0; w < 16; ++w) s += hist[w][tid];
    hist[0][tid] = s;
  }
  __syncthreads();
  if (tid == 0) {
    unsigned int run = 0;
    int bin = 255;
    for (; bin >= 0; --bin) {
      unsigned int h = hist[0][bin];
      if (run + h >= (unsigned int)k) {
        s_bin = bin;
        s_cntGT = (int)run;
        s_refine = (run + h > (unsigned int)CAP) ? 1 : 0;
        break;
      }
      run += h;
    }
    if (bin < 0) { s_bin = 0; s_cntGT = 0; s_refine = 0; }
    s_cnt = 0;
  }
  __syncthreads();
  const unsigned int binq = (unsigned int)s_bin;
  unsigned int tau16;

  if (s_refine) {
    // pass 1b: 2nd-byte histogram restricted to elements in the boundary bin
    __syncthreads();
    for (int i = tid; i < 16 * 256; i += 1024) ((unsigned int*)hist)[i] = 0u;
    __syncthreads();
    for (int i = tid * 4; i < V; i += 4096) {
      f32x4 v4 = *(const f32x4*)(row + i);
#pragma unroll
      for (int e = 0; e < 4; ++e) {
        unsigned int u = f2ord(v4[e]);
        if ((u >> 24) == binq) atomicAdd(&hist[wv][(u >> 16) & 255u], 1u);
      }
    }
    __syncthreads();
    if (tid < 256) {
      unsigned int s = 0;
      for (int w = 0; w < 16; ++w) s += hist[w][tid];
      hist[0][tid] = s;
    }
    __syncthreads();
    if (tid == 0) {
      int need = k - s_cntGT;  // >= 1
      unsigned int run = 0;
      int sub = 255;
      for (; sub >= 0; --sub) {
        unsigned int h = hist[0][sub];
        if (run + h >= (unsigned int)need) break;
        run += h;
      }
      if (sub < 0) sub = 0;
      s_tau = (binq << 8) | (unsigned int)sub;
    }
    __syncthreads();
    tau16 = s_tau;
  } else {
    tau16 = binq << 8;
  }

  // pass 2: gather all elements with 16-bit ordered prefix >= tau16
  for (int i = tid * 4; i < V; i += 4096) {
    f32x4 v4 = *(const f32x4*)(row + i);
#pragma unroll
    for (int e = 0; e < 4; ++e) {
      float x = v4[e];
      if ((f2ord(x) >> 16) >= tau16) {
        int p = atomicAdd(&s_cnt, 1);
        if (p < CAP) {
          cvals[(size_t)b * CAP + p] = x;
          cidx[(size_t)b * CAP + p] = i + e;
        }
      }
    }
  }
  __syncthreads();
  if (tid == 0) ccnt[b] = (s_cnt < CAP) ? s_cnt : CAP;
}

// ---------- K3: zero row, sort candidates, top-k/top-p, scatter, gumbel ----
__global__ __launch_bounds__(1024) void finalize_k(
    const float* __restrict__ cvals, const int* __restrict__ cidx,
    const int* __restrict__ ccnt, const int* __restrict__ top_ks,
    const float* __restrict__ temps, const float* __restrict__ top_ps,
    float* __restrict__ out, int probs_base, int V, unsigned int half_n) {
  const int b = blockIdx.x, tid = threadIdx.x;
  __shared__ float vals[CAP];
  __shared__ int idxs[CAP];
  __shared__ float ex[1024];
  __shared__ float pr[1024];
  __shared__ float rsc[1024];
  __shared__ int rid[1024];
  __shared__ float s_S, s_S2;
  __shared__ int s_m;

  const int cnt = ccnt[b];
  int k = top_ks[b];
  if (k < 1) k = 1;
  if (k > V) k = V;
  int K = (k < cnt) ? k : cnt;
  if (K > 1024) K = 1024;

  for (int i = tid; i < CAP; i += 1024) {
    if (i < cnt) { vals[i] = cvals[(size_t)b * CAP + i]; idxs[i] = cidx[(size_t)b * CAP + i]; }
    else         { vals[i] = -INFINITY;                  idxs[i] = 0x7fffffff; }
  }

  // zero this row's probs (replaces global memset; overlaps with sort)
  {
    float* rowp = out + (size_t)probs_base + (size_t)b * V;
    const f32x4 z = (f32x4){0.f, 0.f, 0.f, 0.f};
    for (int i = tid * 4; i < V; i += 4096) *(f32x4*)(rowp + i) = z;
  }
  __syncthreads();

  // bitonic sort: (val desc, idx asc) == stable argsort(-logits)
  for (int size = 2; size <= CAP; size <<= 1) {
    for (int stride = size >> 1; stride > 0; stride >>= 1) {
      for (int i = tid; i < CAP; i += 1024) {
        int j = i ^ stride;
        if (j > i) {
          float vi = vals[i], vj = vals[j];
          int ii = idxs[i], ij = idxs[j];
          bool iBeforeJ = (vi > vj) || (vi == vj && ii < ij);
          bool up = ((i & size) == 0);
          if (up ? !iBeforeJ : iBeforeJ) {
            vals[i] = vj; idxs[i] = ij; vals[j] = vi; idxs[j] = ii;
          }
        }
      }
      __syncthreads();
    }
  }

  const float t = temps[b];
  const float tt = (t < 1e-5f) ? 1.0f : t;
  const float l0 = vals[0] / tt;
  for (int i = tid; i < K; i += 1024) ex[i] = expf(vals[i] / tt - l0);
  __syncthreads();

  if (tid == 0) {
    float S = 0.f;
    for (int i = 0; i < K; ++i) S += ex[i];
    s_S = S;
  }
  __syncthreads();
  const float S = s_S;
  for (int i = tid; i < K; i += 1024) pr[i] = ex[i] / S;
  __syncthreads();

  if (tid == 0) {
    float p = top_ps[b];
    int m;
    if (p >= 1.0f - 1e-5f) m = K;
    else {
      m = 1;
      float cum = pr[0];
      for (int i = 1; i < K; ++i) {
        cum += pr[i];
        if (cum <= p) m++; else break;
      }
    }
    s_m = m;
  }
  __syncthreads();
  const int m = s_m;

  {
    float loc = 0.f;
    for (int i = tid; i < m; i += 1024) loc += ex[i];
    rsc[tid] = loc;
    __syncthreads();
    for (int s = 512; s > 0; s >>= 1) {
      if (tid < s) rsc[tid] += rsc[tid + s];
      __syncthreads();
    }
    if (tid == 0) s_S2 = rsc[0];
    __syncthreads();
  }
  const float S2 = s_S2;

  for (int i = tid; i < m; i += 1024)
    out[(size_t)probs_base + (size_t)b * V + idxs[i]] = ex[i] / S2;

  float best = -INFINITY;
  int bestV = 0x7fffffff;
  for (int i = tid; i < m; i += 1024) {
    int vv = idxs[i];
    unsigned int flat = (unsigned int)b * (unsigned int)V + (unsigned int)vv;
    float g = gumbel_at(flat, half_n);
    float sc = vals[i] / tt + g;
    if (sc > best || (sc == best && vv < bestV)) { best = sc; bestV = vv; }
  }
  rsc[tid] = best; rid[tid] = bestV;
  __syncthreads();
  for (int s = 512; s > 0; s >>= 1) {
    if (tid < s) {
      float o = rsc[tid + s]; int oi = rid[tid + s];
      if (o > rsc[tid] || (o == rsc[tid] && oi < rid[tid])) { rsc[tid] = o; rid[tid] = oi; }
    }
    __syncthreads();
  }
  if (tid == 0) {
    int token = (t < 1e-5f) ? idxs[0] : rid[0];
    if (token < 0 || token >= V) token = 0;
    out[b] = (float)token;
  }
}

// ---------- launch ----------
extern "C" void kernel_launch(void* const* d_in, const int* in_sizes, int n_in,
                              void* d_out, int out_size, void* d_ws, size_t ws_size,
                              hipStream_t stream) {
  const float* hidden = (const float*)d_in[0];
  const float* emb    = (const float*)d_in[1];
  const int*   lti    = (const int*)d_in[2];
  const float* temps  = (const float*)d_in[3];
  const float* tops   = (const float*)d_in[4];
  const int*   topks  = (const int*)d_in[5];

  const int B = in_sizes[2];
  const int V = (int)(((long long)out_size - B) / B);
  const int D = in_sizes[1] / V;
  const int probs_base = out_size - B * V;  // = B
  const unsigned int half_n = (unsigned int)(((long long)B * V) / 2);

  float* out = (float*)d_out;

  char* ws = (char*)d_ws;
  size_t off = 0;
  unsigned short* Ah = (unsigned short*)(ws + off); off += (size_t)B * D * sizeof(unsigned short);
  unsigned short* Al = (unsigned short*)(ws + off); off += (size_t)B * D * sizeof(unsigned short);
  float* cvals = (float*)(ws + off); off += (size_t)B * CAP * sizeof(float);
  int* cidx = (int*)(ws + off);      off += (size_t)B * CAP * sizeof(int);
  int* ccnt = (int*)(ws + off);      off += (size_t)B * sizeof(int);
  (void)ws_size; (void)n_in;

  float* logits = out + probs_base;

  hipLaunchKernelGGL(gather_split, dim3(B), dim3(256), 0, stream, hidden, lti, Ah, Al, D);
  // MEASUREMENT ROUND: gemm launched TWICE (idempotent — rewrites identical
  // logits before any consumer). gemm_dur = dur_R9 - 435us (R5 baseline).
  hipLaunchKernelGGL(gemm_mfma, dim3(V / BN), dim3(256), 0, stream, Ah, Al, emb, logits, D, V);
  hipLaunchKernelGGL(gemm_mfma, dim3(V / BN), dim3(256), 0, stream, Ah, Al, emb, logits, D, V);
  hipLaunchKernelGGL(select_topk, dim3(B), dim3(1024), 0, stream, logits, topks, cvals, cidx, ccnt, V);
  hipLaunchKernelGGL(finalize_k, dim3(B), dim3(1024), 0, stream, cvals, cidx, ccnt,
                     topks, temps, tops, out, probs_base, V, half_n);
}

// Round 10
// 457.925 us; speedup vs baseline: 1.4461x; 1.4461x over previous
//
#include <hip/hip_runtime.h>
#include <hip/hip_bf16.h>
#include <math.h>

#define CAP 2048
#define PRNG_PARTITIONABLE 1

typedef __attribute__((ext_vector_type(8))) short bf16x8;
typedef __attribute__((ext_vector_type(4))) float f32x4;
typedef __attribute__((ext_vector_type(4))) unsigned int u32x4;

union B8U4 { u32x4 u; bf16x8 b; };

// ---------- helpers ----------
__device__ __forceinline__ unsigned int f2ord(float x) {
  unsigned int u = __float_as_uint(x);
  return (u & 0x80000000u) ? ~u : (u | 0x80000000u);
}

__device__ __forceinline__ unsigned int rotl_u32(unsigned int x, int r) {
  return (x << r) | (x >> (32 - r));
}

__device__ float gumbel_at(unsigned int flat, unsigned int half_n) {
  const unsigned int ks0 = 0u;
  const unsigned int ks1 = 42u;
  const unsigned int ks2 = 0x1BD11BDAu ^ ks0 ^ ks1;
  unsigned int x0, x1;
#if PRNG_PARTITIONABLE
  x0 = 0u;
  x1 = flat;
#else
  unsigned int cnt = (flat < half_n) ? flat : (flat - half_n);
  x0 = cnt; x1 = cnt + half_n;
#endif
  x0 += ks0; x1 += ks1;
#define TF_R(r) { x0 += x1; x1 = rotl_u32(x1, r); x1 ^= x0; }
  TF_R(13) TF_R(15) TF_R(26) TF_R(6)
  x0 += ks1; x1 += ks2 + 1u;
  TF_R(17) TF_R(29) TF_R(16) TF_R(24)
  x0 += ks2; x1 += ks0 + 2u;
  TF_R(13) TF_R(15) TF_R(26) TF_R(6)
  x0 += ks0; x1 += ks1 + 3u;
  TF_R(17) TF_R(29) TF_R(16) TF_R(24)
  x0 += ks1; x1 += ks2 + 4u;
  TF_R(13) TF_R(15) TF_R(26) TF_R(6)
  x0 += ks2; x1 += ks0 + 5u;
#undef TF_R
#if PRNG_PARTITIONABLE
  unsigned int bits = x0 ^ x1;
#else
  unsigned int bits = (flat < half_n) ? x0 : x1;
#endif
  float f = __uint_as_float(0x3f800000u | (bits >> 9)) - 1.0f;
  float u = fmaxf(1e-20f, f + 1e-20f);
  return -logf(-logf(u));
}

__device__ __forceinline__ unsigned short f32_to_bf16_rne(float x) {
  unsigned int u = __float_as_uint(x);
  unsigned int r = u + 0x7fffu + ((u >> 16) & 1u);
  return (unsigned short)(r >> 16);
}
__device__ __forceinline__ float bf16u_to_f32(unsigned short h) {
  return __uint_as_float(((unsigned int)h) << 16);
}

struct HL { unsigned int h, l; };
__device__ __forceinline__ HL cvt_pair(float a, float b) {
  float2 xf = make_float2(a, b);
  __hip_bfloat162 hh = __float22bfloat162_rn(xf);
  float2 hf = __bfloat1622float2(hh);
  __hip_bfloat162 ll = __float22bfloat162_rn(make_float2(a - hf.x, b - hf.y));
  HL r;
  __builtin_memcpy(&r.h, &hh, 4);
  __builtin_memcpy(&r.l, &ll, 4);
  return r;
}

__device__ __forceinline__ f32x4 mfma16(bf16x8 a, bf16x8 b, f32x4 c) {
  return __builtin_amdgcn_mfma_f32_16x16x32_bf16(a, b, c, 0, 0, 0);
}

// ---------- K0: gather last-token rows + split to bf16 hi/lo ----------
__global__ void gather_split(const float* __restrict__ hidden, const int* __restrict__ lti,
                             unsigned short* __restrict__ Ah, unsigned short* __restrict__ Al,
                             int D) {
  int b = blockIdx.x;
  const float* src = hidden + (size_t)lti[b] * D;
  for (int i = threadIdx.x; i < D; i += blockDim.x) {
    float x = src[i];
    unsigned short h = f32_to_bf16_rne(x);
    float r = x - bf16u_to_f32(h);
    Ah[(size_t)b * D + i] = h;
    Al[(size_t)b * D + i] = f32_to_bf16_rne(r);
  }
}

// ---------- K1: logits = A @ E^T via bf16x3 MFMA (R5 structure, 227us) ----
// BM=64, BN=128, BK=64. 4 waves; wave w owns n in [w*32, w*32+32).
// B raw f32 in LDS (convert-on-read under MFMA shadow); reg ping-pong prefetch.
#define BN 128
#define BK 64
__global__ __launch_bounds__(256) void gemm_mfma(
    const unsigned short* __restrict__ Ahg, const unsigned short* __restrict__ Alg,
    const float* __restrict__ E, float* __restrict__ outL, int D, int V) {
  __shared__ __align__(16) float BS[128 * 64];
  __shared__ __align__(16) unsigned short AhS[64 * 64];
  __shared__ __align__(16) unsigned short AlS[64 * 64];

  const int t = threadIdx.x;
  const int lane = t & 63;
  const int wv = t >> 6;
  const long n0 = (long)blockIdx.x * BN;
  const int am = t >> 2, ao = t & 3;

  f32x4 acc[4][2];
#pragma unroll
  for (int i = 0; i < 4; ++i)
#pragma unroll
    for (int j = 0; j < 2; ++j) acc[i][j] = (f32x4){0.f, 0.f, 0.f, 0.f};

  f32x4 bA[8], bB[8];
  bf16x8 aA[4], aB[4];

  auto LOAD = [&](f32x4* br, bf16x8* ar, int k0) {
#pragma unroll
    for (int q = 0; q < 4; ++q) {
      int gi = q * 256 + t, n = gi >> 3, o = gi & 7;
      const float* s = E + (size_t)(n0 + n) * D + k0 + o * 8;
      br[2 * q] = *(const f32x4*)s;
      br[2 * q + 1] = *(const f32x4*)(s + 4);
    }
    const unsigned short* ph = Ahg + (size_t)am * D + k0 + ao * 16;
    ar[0] = *(const bf16x8*)ph;
    ar[1] = *(const bf16x8*)(ph + 8);
    const unsigned short* pl = Alg + (size_t)am * D + k0 + ao * 16;
    ar[2] = *(const bf16x8*)pl;
    ar[3] = *(const bf16x8*)(pl + 8);
  };

  auto STAGE = [&](f32x4* br, bf16x8* ar) {
#pragma unroll
    for (int q = 0; q < 4; ++q) {
      int gi = q * 256 + t, n = gi >> 3, o = gi & 7;
      int pg0 = (2 * o) ^ (n & 7);
      int pg1 = (2 * o + 1) ^ (n & 7);
      *(f32x4*)&BS[n * 64 + pg0 * 4] = br[2 * q];
      *(f32x4*)&BS[n * 64 + pg1 * 4] = br[2 * q + 1];
    }
    int g0 = ao * 2;
    int off0 = am * 64 + ((g0 ^ (am & 7)) * 8);
    int off1 = am * 64 + (((g0 + 1) ^ (am & 7)) * 8);
    *(bf16x8*)&AhS[off0] = ar[0];
    *(bf16x8*)&AhS[off1] = ar[1];
    *(bf16x8*)&AlS[off0] = ar[2];
    *(bf16x8*)&AlS[off1] = ar[3];
  };

  auto COMPUTE = [&]() {
#pragma unroll
    for (int k32 = 0; k32 < 2; ++k32) {
      const int og = k32 * 4 + (lane >> 4);
      bf16x8 ah[4], al[4], bh[2], bl[2];
#pragma unroll
      for (int mf = 0; mf < 4; ++mf) {
        int r = mf * 16 + (lane & 15);
        int off = r * 64 + ((og ^ (r & 7)) * 8);
        ah[mf] = *(const bf16x8*)&AhS[off];
        al[mf] = *(const bf16x8*)&AlS[off];
      }
#pragma unroll
      for (int nf = 0; nf < 2; ++nf) {
        int n = wv * 32 + nf * 16 + (lane & 15);
        int pg0 = (2 * og) ^ (n & 7);
        int pg1 = (2 * og + 1) ^ (n & 7);
        f32x4 v0 = *(const f32x4*)&BS[n * 64 + pg0 * 4];
        f32x4 v1 = *(const f32x4*)&BS[n * 64 + pg1 * 4];
        HL p0 = cvt_pair(v0.x, v0.y);
        HL p1 = cvt_pair(v0.z, v0.w);
        HL p2 = cvt_pair(v1.x, v1.y);
        HL p3 = cvt_pair(v1.z, v1.w);
        B8U4 hb, lb;
        hb.u = (u32x4){p0.h, p1.h, p2.h, p3.h};
        lb.u = (u32x4){p0.l, p1.l, p2.l, p3.l};
        bh[nf] = hb.b;
        bl[nf] = lb.b;
      }
      __builtin_amdgcn_s_setprio(1);
#pragma unroll
      for (int mf = 0; mf < 4; ++mf)
#pragma unroll
        for (int nf = 0; nf < 2; ++nf) {
          acc[mf][nf] = mfma16(ah[mf], bh[nf], acc[mf][nf]);
          acc[mf][nf] = mfma16(ah[mf], bl[nf], acc[mf][nf]);
          acc[mf][nf] = mfma16(al[mf], bh[nf], acc[mf][nf]);
        }
      __builtin_amdgcn_s_setprio(0);
    }
  };

  LOAD(bA, aA, 0);
#pragma unroll 1
  for (int k0 = 0; k0 < D; k0 += 2 * BK) {
    if (k0 + BK < D) LOAD(bB, aB, k0 + BK);
    __syncthreads();
    STAGE(bA, aA);
    __syncthreads();
    COMPUTE();
    if (k0 + 2 * BK < D) LOAD(bA, aA, k0 + 2 * BK);
    __syncthreads();
    STAGE(bB, aB);
    __syncthreads();
    COMPUTE();
  }

  // epilogue: D layout col=lane&15, row=(lane>>4)*4+reg
#pragma unroll
  for (int mf = 0; mf < 4; ++mf)
#pragma unroll
    for (int nf = 0; nf < 2; ++nf) {
      long v = n0 + wv * 32 + nf * 16 + (lane & 15);
      int rbase = mf * 16 + ((lane >> 4) << 2);
#pragma unroll
      for (int reg = 0; reg < 4; ++reg)
        outL[(size_t)(rbase + reg) * V + v] = acc[mf][nf][reg];
    }
}

// ---------- K2a: per-chunk top-byte histogram (8 blocks/row) ----------
__global__ __launch_bounds__(256) void hist_k(
    const float* __restrict__ logits, unsigned int* __restrict__ ghist, int V) {
  const int b = blockIdx.x >> 3, c = blockIdx.x & 7;
  const int CH = V >> 3;
  const float* row = logits + (size_t)b * V;
  __shared__ unsigned int lh[4][256];
  const int tid = threadIdx.x, wv = tid >> 6;
  for (int i = tid; i < 1024; i += 256) ((unsigned int*)lh)[i] = 0u;
  __syncthreads();
  const int base = c * CH;
  for (int i = base + tid * 4; i < base + CH; i += 1024) {
    f32x4 v = *(const f32x4*)(row + i);
    atomicAdd(&lh[wv][f2ord(v.x) >> 24], 1u);
    atomicAdd(&lh[wv][f2ord(v.y) >> 24], 1u);
    atomicAdd(&lh[wv][f2ord(v.z) >> 24], 1u);
    atomicAdd(&lh[wv][f2ord(v.w) >> 24], 1u);
  }
  __syncthreads();
  if (tid < 256) {
    unsigned int s = lh[0][tid] + lh[1][tid] + lh[2][tid] + lh[3][tid];
    if (s) atomicAdd(&ghist[b * 256 + tid], s);
  }
}

// ---------- K2b: per-row threshold (rare in-block 2nd-byte refine) ----------
__global__ __launch_bounds__(256) void thresh_k(
    const float* __restrict__ logits, const unsigned int* __restrict__ ghist,
    const int* __restrict__ top_ks, unsigned int* __restrict__ tau16, int V) {
  const int b = blockIdx.x, tid = threadIdx.x;
  __shared__ unsigned int h[256];
  __shared__ unsigned int h2[4][256];
  __shared__ int s_bin, s_need, s_refine;
  if (tid < 256) h[tid] = ghist[b * 256 + tid];
  __syncthreads();
  if (tid == 0) {
    int k = top_ks[b];
    if (k < 1) k = 1;
    if (k > V) k = V;
    unsigned int run = 0;
    int bin = 255;
    for (; bin >= 0; --bin) {
      unsigned int hh = h[bin];
      if (run + hh >= (unsigned int)k) break;
      run += hh;
    }
    if (bin < 0) bin = 0;
    s_bin = bin;
    s_need = k - (int)run;
    s_refine = (run + h[bin] > (unsigned int)CAP) ? 1 : 0;
    if (!s_refine) tau16[b] = ((unsigned int)bin) << 8;
  }
  __syncthreads();
  if (!s_refine) return;

  const int wv = tid >> 6;
  for (int i = tid; i < 1024; i += 256) ((unsigned int*)h2)[i] = 0u;
  __syncthreads();
  const unsigned int binq = (unsigned int)s_bin;
  const float* row = logits + (size_t)b * V;
  for (int i = tid * 4; i < V; i += 1024) {
    f32x4 v = *(const f32x4*)(row + i);
#pragma unroll
    for (int e = 0; e < 4; ++e) {
      unsigned int u = f2ord(v[e]);
      if ((u >> 24) == binq) atomicAdd(&h2[wv][(u >> 16) & 255u], 1u);
    }
  }
  __syncthreads();
  if (tid == 0) {
    int need = s_need;
    unsigned int run = 0;
    int sub = 255;
    for (; sub >= 0; --sub) {
      unsigned int hh = h2[0][sub] + h2[1][sub] + h2[2][sub] + h2[3][sub];
      if (run + hh >= (unsigned int)need) break;
      run += hh;
    }
    if (sub < 0) sub = 0;
    tau16[b] = (binq << 8) | (unsigned int)sub;
  }
}

// ---------- K2c: gather candidates + zero chunk (8 blocks/row) ----------
__global__ __launch_bounds__(256) void gather_k(
    float* __restrict__ logits, const unsigned int* __restrict__ tau16,
    float* __restrict__ cvals, int* __restrict__ cidx, int* __restrict__ ccnt, int V) {
  const int b = blockIdx.x >> 3, c = blockIdx.x & 7;
  const int CH = V >> 3;
  float* row = logits + (size_t)b * V;
  __shared__ float bv[CAP];
  __shared__ int bi[CAP];
  __shared__ int s_c, s_base;
  const int tid = threadIdx.x;
  if (tid == 0) s_c = 0;
  __syncthreads();
  const unsigned int tau = tau16[b];
  const int base = c * CH;
  const f32x4 z = (f32x4){0.f, 0.f, 0.f, 0.f};
  for (int i = base + tid * 4; i < base + CH; i += 1024) {
    f32x4 v = *(const f32x4*)(row + i);
#pragma unroll
    for (int e = 0; e < 4; ++e) {
      float x = v[e];
      if ((f2ord(x) >> 16) >= tau) {
        int p = atomicAdd(&s_c, 1);
        if (p < CAP) { bv[p] = x; bi[p] = i + e; }
      }
    }
    *(f32x4*)(row + i) = z;  // zero for probs scatter
  }
  __syncthreads();
  int cnt = s_c;
  if (cnt > CAP) cnt = CAP;
  if (tid == 0) s_base = atomicAdd(ccnt + b, cnt);
  __syncthreads();
  const int gb = s_base;
  for (int i = tid; i < cnt; i += 256) {
    int p = gb + i;
    if (p < CAP) {
      cvals[(size_t)b * CAP + p] = bv[i];
      cidx[(size_t)b * CAP + p] = bi[i];
    }
  }
}

// ---------- K3: sort candidates, top-k/top-p, scatter, gumbel ----------
__global__ __launch_bounds__(1024) void finalize_k(
    const float* __restrict__ cvals, const int* __restrict__ cidx,
    const int* __restrict__ ccnt, const int* __restrict__ top_ks,
    const float* __restrict__ temps, const float* __restrict__ top_ps,
    float* __restrict__ out, int probs_base, int V, unsigned int half_n) {
  const int b = blockIdx.x, tid = threadIdx.x;
  __shared__ float vals[CAP];
  __shared__ int idxs[CAP];
  __shared__ float ex[1024];
  __shared__ float pr[1024];
  __shared__ float rsc[1024];
  __shared__ int rid[1024];
  __shared__ float s_S, s_S2;
  __shared__ int s_m;

  int cnt = ccnt[b];
  if (cnt > CAP) cnt = CAP;
  int k = top_ks[b];
  if (k < 1) k = 1;
  if (k > V) k = V;
  int K = (k < cnt) ? k : cnt;
  if (K > 1024) K = 1024;

  for (int i = tid; i < CAP; i += 1024) {
    if (i < cnt) { vals[i] = cvals[(size_t)b * CAP + i]; idxs[i] = cidx[(size_t)b * CAP + i]; }
    else         { vals[i] = -INFINITY;                  idxs[i] = 0x7fffffff; }
  }
  __syncthreads();

  // bitonic sort: (val desc, idx asc) == stable argsort(-logits)
  for (int size = 2; size <= CAP; size <<= 1) {
    for (int stride = size >> 1; stride > 0; stride >>= 1) {
      for (int i = tid; i < CAP; i += 1024) {
        int j = i ^ stride;
        if (j > i) {
          float vi = vals[i], vj = vals[j];
          int ii = idxs[i], ij = idxs[j];
          bool iBeforeJ = (vi > vj) || (vi == vj && ii < ij);
          bool up = ((i & size) == 0);
          if (up ? !iBeforeJ : iBeforeJ) {
            vals[i] = vj; idxs[i] = ij; vals[j] = vi; idxs[j] = ii;
          }
        }
      }
      __syncthreads();
    }
  }

  const float t = temps[b];
  const float tt = (t < 1e-5f) ? 1.0f : t;
  const float l0 = vals[0] / tt;
  for (int i = tid; i < K; i += 1024) ex[i] = expf(vals[i] / tt - l0);
  __syncthreads();

  if (tid == 0) {
    float S = 0.f;
    for (int i = 0; i < K; ++i) S += ex[i];
    s_S = S;
  }
  __syncthreads();
  const float S = s_S;
  for (int i = tid; i < K; i += 1024) pr[i] = ex[i] / S;
  __syncthreads();

  if (tid == 0) {
    float p = top_ps[b];
    int m;
    if (p >= 1.0f - 1e-5f) m = K;
    else {
      m = 1;
      float cum = pr[0];
      for (int i = 1; i < K; ++i) {
        cum += pr[i];
        if (cum <= p) m++; else break;
      }
    }
    s_m = m;
  }
  __syncthreads();
  const int m = s_m;

  {
    float loc = 0.f;
    for (int i = tid; i < m; i += 1024) loc += ex[i];
    rsc[tid] = loc;
    __syncthreads();
    for (int s = 512; s > 0; s >>= 1) {
      if (tid < s) rsc[tid] += rsc[tid + s];
      __syncthreads();
    }
    if (tid == 0) s_S2 = rsc[0];
    __syncthreads();
  }
  const float S2 = s_S2;

  for (int i = tid; i < m; i += 1024)
    out[(size_t)probs_base + (size_t)b * V + idxs[i]] = ex[i] / S2;

  float best = -INFINITY;
  int bestV = 0x7fffffff;
  for (int i = tid; i < m; i += 1024) {
    int vv = idxs[i];
    unsigned int flat = (unsigned int)b * (unsigned int)V + (unsigned int)vv;
    float g = gumbel_at(flat, half_n);
    float sc = vals[i] / tt + g;
    if (sc > best || (sc == best && vv < bestV)) { best = sc; bestV = vv; }
  }
  rsc[tid] = best; rid[tid] = bestV;
  __syncthreads();
  for (int s = 512; s > 0; s >>= 1) {
    if (tid < s) {
      float o = rsc[tid + s]; int oi = rid[tid + s];
      if (o > rsc[tid] || (o == rsc[tid] && oi < rid[tid])) { rsc[tid] = o; rid[tid] = oi; }
    }
    __syncthreads();
  }
  if (tid == 0) {
    int token = (t < 1e-5f) ? idxs[0] : rid[0];
    if (token < 0 || token >= V) token = 0;
    out[b] = (float)token;
  }
}

// ---------- launch ----------
extern "C" void kernel_launch(void* const* d_in, const int* in_sizes, int n_in,
                              void* d_out, int out_size, void* d_ws, size_t ws_size,
                              hipStream_t stream) {
  const float* hidden = (const float*)d_in[0];
  const float* emb    = (const float*)d_in[1];
  const int*   lti    = (const int*)d_in[2];
  const float* temps  = (const float*)d_in[3];
  const float* tops   = (const float*)d_in[4];
  const int*   topks  = (const int*)d_in[5];

  const int B = in_sizes[2];
  const int V = (int)(((long long)out_size - B) / B);
  const int D = in_sizes[1] / V;
  const int probs_base = out_size - B * V;  // = B
  const unsigned int half_n = (unsigned int)(((long long)B * V) / 2);

  float* out = (float*)d_out;

  char* ws = (char*)d_ws;
  size_t off = 0;
  unsigned short* Ah = (unsigned short*)(ws + off); off += (size_t)B * D * sizeof(unsigned short);
  unsigned short* Al = (unsigned short*)(ws + off); off += (size_t)B * D * sizeof(unsigned short);
  float* cvals = (float*)(ws + off); off += (size_t)B * CAP * sizeof(float);
  int* cidx = (int*)(ws + off);      off += (size_t)B * CAP * sizeof(int);
  // zeroed region: ccnt | ghist | tau16 (contiguous, one memsetAsync)
  char* zbase = ws + off;
  int* ccnt = (int*)(ws + off);              off += (size_t)B * sizeof(int);
  unsigned int* ghist = (unsigned int*)(ws + off); off += (size_t)B * 256 * sizeof(unsigned int);
  unsigned int* tau16 = (unsigned int*)(ws + off); off += (size_t)B * sizeof(unsigned int);
  const size_t zbytes = (size_t)(B + B * 256 + B) * sizeof(unsigned int);
  (void)ws_size; (void)n_in;

  float* logits = out + probs_base;

  hipLaunchKernelGGL(gather_split, dim3(B), dim3(256), 0, stream, hidden, lti, Ah, Al, D);
  hipMemsetAsync(zbase, 0, zbytes, stream);
  hipLaunchKernelGGL(gemm_mfma, dim3(V / BN), dim3(256), 0, stream, Ah, Al, emb, logits, D, V);
  hipLaunchKernelGGL(hist_k, dim3(8 * B), dim3(256), 0, stream, logits, ghist, V);
  hipLaunchKernelGGL(thresh_k, dim3(B), dim3(256), 0, stream, logits, ghist, topks, tau16, V);
  hipLaunchKernelGGL(gather_k, dim3(8 * B), dim3(256), 0, stream, logits, tau16, cvals, cidx, ccnt, V);
  hipLaunchKernelGGL(finalize_k, dim3(B), dim3(1024), 0, stream, cvals, cidx, ccnt,
                     topks, temps, tops, out, probs_base, V, half_n);
}

// Round 11
// 348.550 us; speedup vs baseline: 1.8999x; 1.3138x over previous
//
#include <hip/hip_runtime.h>
#include <hip/hip_bf16.h>
#include <math.h>

#define CAP 2048
#define PRNG_PARTITIONABLE 1

typedef __attribute__((ext_vector_type(8))) short bf16x8;
typedef __attribute__((ext_vector_type(4))) float f32x4;
typedef __attribute__((ext_vector_type(4))) unsigned int u32x4;

union B8U4 { u32x4 u; bf16x8 b; };

// ---------- helpers ----------
__device__ __forceinline__ unsigned int f2ord(float x) {
  unsigned int u = __float_as_uint(x);
  return (u & 0x80000000u) ? ~u : (u | 0x80000000u);
}

__device__ __forceinline__ unsigned int rotl_u32(unsigned int x, int r) {
  return (x << r) | (x >> (32 - r));
}

__device__ float gumbel_at(unsigned int flat, unsigned int half_n) {
  const unsigned int ks0 = 0u;
  const unsigned int ks1 = 42u;
  const unsigned int ks2 = 0x1BD11BDAu ^ ks0 ^ ks1;
  unsigned int x0, x1;
#if PRNG_PARTITIONABLE
  x0 = 0u;
  x1 = flat;
#else
  unsigned int cnt = (flat < half_n) ? flat : (flat - half_n);
  x0 = cnt; x1 = cnt + half_n;
#endif
  x0 += ks0; x1 += ks1;
#define TF_R(r) { x0 += x1; x1 = rotl_u32(x1, r); x1 ^= x0; }
  TF_R(13) TF_R(15) TF_R(26) TF_R(6)
  x0 += ks1; x1 += ks2 + 1u;
  TF_R(17) TF_R(29) TF_R(16) TF_R(24)
  x0 += ks2; x1 += ks0 + 2u;
  TF_R(13) TF_R(15) TF_R(26) TF_R(6)
  x0 += ks0; x1 += ks1 + 3u;
  TF_R(17) TF_R(29) TF_R(16) TF_R(24)
  x0 += ks1; x1 += ks2 + 4u;
  TF_R(13) TF_R(15) TF_R(26) TF_R(6)
  x0 += ks2; x1 += ks0 + 5u;
#undef TF_R
#if PRNG_PARTITIONABLE
  unsigned int bits = x0 ^ x1;
#else
  unsigned int bits = (flat < half_n) ? x0 : x1;
#endif
  float f = __uint_as_float(0x3f800000u | (bits >> 9)) - 1.0f;
  float u = fmaxf(1e-20f, f + 1e-20f);
  return -logf(-logf(u));
}

__device__ __forceinline__ unsigned short f32_to_bf16_rne(float x) {
  unsigned int u = __float_as_uint(x);
  unsigned int r = u + 0x7fffu + ((u >> 16) & 1u);
  return (unsigned short)(r >> 16);
}
__device__ __forceinline__ float bf16u_to_f32(unsigned short h) {
  return __uint_as_float(((unsigned int)h) << 16);
}

struct HL { unsigned int h, l; };
__device__ __forceinline__ HL cvt_pair(float a, float b) {
  float2 xf = make_float2(a, b);
  __hip_bfloat162 hh = __float22bfloat162_rn(xf);
  float2 hf = __bfloat1622float2(hh);
  __hip_bfloat162 ll = __float22bfloat162_rn(make_float2(a - hf.x, b - hf.y));
  HL r;
  __builtin_memcpy(&r.h, &hh, 4);
  __builtin_memcpy(&r.l, &ll, 4);
  return r;
}

__device__ __forceinline__ f32x4 mfma16(bf16x8 a, bf16x8 b, f32x4 c) {
  return __builtin_amdgcn_mfma_f32_16x16x32_bf16(a, b, c, 0, 0, 0);
}

// ---------- K0: gather last-token rows + split to bf16 hi/lo ----------
__global__ void gather_split(const float* __restrict__ hidden, const int* __restrict__ lti,
                             unsigned short* __restrict__ Ah, unsigned short* __restrict__ Al,
                             int D) {
  int b = blockIdx.x;
  const float* src = hidden + (size_t)lti[b] * D;
  for (int i = threadIdx.x; i < D; i += blockDim.x) {
    float x = src[i];
    unsigned short h = f32_to_bf16_rne(x);
    float r = x - bf16u_to_f32(h);
    Ah[(size_t)b * D + i] = h;
    Al[(size_t)b * D + i] = f32_to_bf16_rne(r);
  }
}

// ---------- K1: logits = A @ E^T via bf16x3 MFMA (R5 structure, 227us) ----
#define BN 128
#define BK 64
__global__ __launch_bounds__(256) void gemm_mfma(
    const unsigned short* __restrict__ Ahg, const unsigned short* __restrict__ Alg,
    const float* __restrict__ E, float* __restrict__ outL, int D, int V) {
  __shared__ __align__(16) float BS[128 * 64];
  __shared__ __align__(16) unsigned short AhS[64 * 64];
  __shared__ __align__(16) unsigned short AlS[64 * 64];

  const int t = threadIdx.x;
  const int lane = t & 63;
  const int wv = t >> 6;
  const long n0 = (long)blockIdx.x * BN;
  const int am = t >> 2, ao = t & 3;

  f32x4 acc[4][2];
#pragma unroll
  for (int i = 0; i < 4; ++i)
#pragma unroll
    for (int j = 0; j < 2; ++j) acc[i][j] = (f32x4){0.f, 0.f, 0.f, 0.f};

  f32x4 bA[8], bB[8];
  bf16x8 aA[4], aB[4];

  auto LOAD = [&](f32x4* br, bf16x8* ar, int k0) {
#pragma unroll
    for (int q = 0; q < 4; ++q) {
      int gi = q * 256 + t, n = gi >> 3, o = gi & 7;
      const float* s = E + (size_t)(n0 + n) * D + k0 + o * 8;
      br[2 * q] = *(const f32x4*)s;
      br[2 * q + 1] = *(const f32x4*)(s + 4);
    }
    const unsigned short* ph = Ahg + (size_t)am * D + k0 + ao * 16;
    ar[0] = *(const bf16x8*)ph;
    ar[1] = *(const bf16x8*)(ph + 8);
    const unsigned short* pl = Alg + (size_t)am * D + k0 + ao * 16;
    ar[2] = *(const bf16x8*)pl;
    ar[3] = *(const bf16x8*)(pl + 8);
  };

  auto STAGE = [&](f32x4* br, bf16x8* ar) {
#pragma unroll
    for (int q = 0; q < 4; ++q) {
      int gi = q * 256 + t, n = gi >> 3, o = gi & 7;
      int pg0 = (2 * o) ^ (n & 7);
      int pg1 = (2 * o + 1) ^ (n & 7);
      *(f32x4*)&BS[n * 64 + pg0 * 4] = br[2 * q];
      *(f32x4*)&BS[n * 64 + pg1 * 4] = br[2 * q + 1];
    }
    int g0 = ao * 2;
    int off0 = am * 64 + ((g0 ^ (am & 7)) * 8);
    int off1 = am * 64 + (((g0 + 1) ^ (am & 7)) * 8);
    *(bf16x8*)&AhS[off0] = ar[0];
    *(bf16x8*)&AhS[off1] = ar[1];
    *(bf16x8*)&AlS[off0] = ar[2];
    *(bf16x8*)&AlS[off1] = ar[3];
  };

  auto COMPUTE = [&]() {
#pragma unroll
    for (int k32 = 0; k32 < 2; ++k32) {
      const int og = k32 * 4 + (lane >> 4);
      bf16x8 ah[4], al[4], bh[2], bl[2];
#pragma unroll
      for (int mf = 0; mf < 4; ++mf) {
        int r = mf * 16 + (lane & 15);
        int off = r * 64 + ((og ^ (r & 7)) * 8);
        ah[mf] = *(const bf16x8*)&AhS[off];
        al[mf] = *(const bf16x8*)&AlS[off];
      }
#pragma unroll
      for (int nf = 0; nf < 2; ++nf) {
        int n = wv * 32 + nf * 16 + (lane & 15);
        int pg0 = (2 * og) ^ (n & 7);
        int pg1 = (2 * og + 1) ^ (n & 7);
        f32x4 v0 = *(const f32x4*)&BS[n * 64 + pg0 * 4];
        f32x4 v1 = *(const f32x4*)&BS[n * 64 + pg1 * 4];
        HL p0 = cvt_pair(v0.x, v0.y);
        HL p1 = cvt_pair(v0.z, v0.w);
        HL p2 = cvt_pair(v1.x, v1.y);
        HL p3 = cvt_pair(v1.z, v1.w);
        B8U4 hb, lb;
        hb.u = (u32x4){p0.h, p1.h, p2.h, p3.h};
        lb.u = (u32x4){p0.l, p1.l, p2.l, p3.l};
        bh[nf] = hb.b;
        bl[nf] = lb.b;
      }
      __builtin_amdgcn_s_setprio(1);
#pragma unroll
      for (int mf = 0; mf < 4; ++mf)
#pragma unroll
        for (int nf = 0; nf < 2; ++nf) {
          acc[mf][nf] = mfma16(ah[mf], bh[nf], acc[mf][nf]);
          acc[mf][nf] = mfma16(ah[mf], bl[nf], acc[mf][nf]);
          acc[mf][nf] = mfma16(al[mf], bh[nf], acc[mf][nf]);
        }
      __builtin_amdgcn_s_setprio(0);
    }
  };

  LOAD(bA, aA, 0);
#pragma unroll 1
  for (int k0 = 0; k0 < D; k0 += 2 * BK) {
    if (k0 + BK < D) LOAD(bB, aB, k0 + BK);
    __syncthreads();
    STAGE(bA, aA);
    __syncthreads();
    COMPUTE();
    if (k0 + 2 * BK < D) LOAD(bA, aA, k0 + 2 * BK);
    __syncthreads();
    STAGE(bB, aB);
    __syncthreads();
    COMPUTE();
  }

#pragma unroll
  for (int mf = 0; mf < 4; ++mf)
#pragma unroll
    for (int nf = 0; nf < 2; ++nf) {
      long v = n0 + wv * 32 + nf * 16 + (lane & 15);
      int rbase = mf * 16 + ((lane >> 4) << 2);
#pragma unroll
      for (int reg = 0; reg < 4; ++reg)
        outL[(size_t)(rbase + reg) * V + v] = acc[mf][nf][reg];
    }
}

// ---------- K2a: per-chunk top-byte histogram (8 blocks/row) ----------
__global__ __launch_bounds__(256) void hist_k(
    const float* __restrict__ logits, unsigned int* __restrict__ ghist, int V) {
  const int b = blockIdx.x >> 3, c = blockIdx.x & 7;
  const int CH = V >> 3;
  const float* row = logits + (size_t)b * V;
  __shared__ unsigned int lh[4][256];
  const int tid = threadIdx.x, wv = tid >> 6;
  for (int i = tid; i < 1024; i += 256) ((unsigned int*)lh)[i] = 0u;
  __syncthreads();
  const int base = c * CH;
  for (int i = base + tid * 4; i < base + CH; i += 1024) {
    f32x4 v = *(const f32x4*)(row + i);
    atomicAdd(&lh[wv][f2ord(v.x) >> 24], 1u);
    atomicAdd(&lh[wv][f2ord(v.y) >> 24], 1u);
    atomicAdd(&lh[wv][f2ord(v.z) >> 24], 1u);
    atomicAdd(&lh[wv][f2ord(v.w) >> 24], 1u);
  }
  __syncthreads();
  if (tid < 256) {
    unsigned int s = lh[0][tid] + lh[1][tid] + lh[2][tid] + lh[3][tid];
    if (s) atomicAdd(&ghist[b * 256 + tid], s);
  }
}

// ---------- K2b: pick 8-bit bin; set refine flag (tiny) ----------
__global__ __launch_bounds__(256) void thresh1_k(
    const unsigned int* __restrict__ ghist, const int* __restrict__ top_ks,
    unsigned int* __restrict__ tau16, int* __restrict__ bin_b,
    int* __restrict__ need_b, int* __restrict__ refine_b, int V) {
  const int b = blockIdx.x, tid = threadIdx.x;
  __shared__ unsigned int h[256];
  if (tid < 256) h[tid] = ghist[b * 256 + tid];
  __syncthreads();
  if (tid == 0) {
    int k = top_ks[b];
    if (k < 1) k = 1;
    if (k > V) k = V;
    unsigned int run = 0;
    int bin = 255;
    for (; bin >= 0; --bin) {
      unsigned int hh = h[bin];
      if (run + hh >= (unsigned int)k) break;
      run += hh;
    }
    if (bin < 0) bin = 0;
    int refine = (run + h[bin] > (unsigned int)CAP) ? 1 : 0;
    bin_b[b] = bin;
    need_b[b] = k - (int)run;
    refine_b[b] = refine;
    if (!refine) tau16[b] = ((unsigned int)bin) << 8;
  }
}

// ---------- K2c: 2nd-byte histogram of boundary bin (8 blocks/row) ----------
__global__ __launch_bounds__(256) void refine_k(
    const float* __restrict__ logits, const int* __restrict__ bin_b,
    const int* __restrict__ refine_b, unsigned int* __restrict__ ghist2, int V) {
  const int b = blockIdx.x >> 3, c = blockIdx.x & 7;
  if (!refine_b[b]) return;
  const int CH = V >> 3;
  const float* row = logits + (size_t)b * V;
  __shared__ unsigned int lh[4][256];
  const int tid = threadIdx.x, wv = tid >> 6;
  for (int i = tid; i < 1024; i += 256) ((unsigned int*)lh)[i] = 0u;
  __syncthreads();
  const unsigned int binq = (unsigned int)bin_b[b];
  const int base = c * CH;
  for (int i = base + tid * 4; i < base + CH; i += 1024) {
    f32x4 v = *(const f32x4*)(row + i);
#pragma unroll
    for (int e = 0; e < 4; ++e) {
      unsigned int u = f2ord(v[e]);
      if ((u >> 24) == binq) atomicAdd(&lh[wv][(u >> 16) & 255u], 1u);
    }
  }
  __syncthreads();
  if (tid < 256) {
    unsigned int s = lh[0][tid] + lh[1][tid] + lh[2][tid] + lh[3][tid];
    if (s) atomicAdd(&ghist2[b * 256 + tid], s);
  }
}

// ---------- K2d: pick 2nd byte -> tau16 (tiny) ----------
__global__ __launch_bounds__(256) void thresh2_k(
    const unsigned int* __restrict__ ghist2, const int* __restrict__ bin_b,
    const int* __restrict__ need_b, const int* __restrict__ refine_b,
    unsigned int* __restrict__ tau16) {
  const int b = blockIdx.x, tid = threadIdx.x;
  if (!refine_b[b]) return;
  __shared__ unsigned int h[256];
  if (tid < 256) h[tid] = ghist2[b * 256 + tid];
  __syncthreads();
  if (tid == 0) {
    int need = need_b[b];
    unsigned int run = 0;
    int sub = 255;
    for (; sub >= 0; --sub) {
      unsigned int hh = h[sub];
      if (run + hh >= (unsigned int)need) break;
      run += hh;
    }
    if (sub < 0) sub = 0;
    tau16[b] = (((unsigned int)bin_b[b]) << 8) | (unsigned int)sub;
  }
}

// ---------- K2e: gather candidates + zero chunk (8 blocks/row) ----------
__global__ __launch_bounds__(256) void gather_k(
    float* __restrict__ logits, const unsigned int* __restrict__ tau16,
    float* __restrict__ cvals, int* __restrict__ cidx, int* __restrict__ ccnt, int V) {
  const int b = blockIdx.x >> 3, c = blockIdx.x & 7;
  const int CH = V >> 3;
  float* row = logits + (size_t)b * V;
  __shared__ float bv[CAP];
  __shared__ int bi[CAP];
  __shared__ int s_c, s_base;
  const int tid = threadIdx.x;
  if (tid == 0) s_c = 0;
  __syncthreads();
  const unsigned int tau = tau16[b];
  const int base = c * CH;
  const f32x4 z = (f32x4){0.f, 0.f, 0.f, 0.f};
  for (int i = base + tid * 4; i < base + CH; i += 1024) {
    f32x4 v = *(const f32x4*)(row + i);
#pragma unroll
    for (int e = 0; e < 4; ++e) {
      float x = v[e];
      if ((f2ord(x) >> 16) >= tau) {
        int p = atomicAdd(&s_c, 1);
        if (p < CAP) { bv[p] = x; bi[p] = i + e; }
      }
    }
    *(f32x4*)(row + i) = z;
  }
  __syncthreads();
  int cnt = s_c;
  if (cnt > CAP) cnt = CAP;
  if (tid == 0) s_base = atomicAdd(ccnt + b, cnt);
  __syncthreads();
  const int gb = s_base;
  for (int i = tid; i < cnt; i += 256) {
    int p = gb + i;
    if (p < CAP) {
      cvals[(size_t)b * CAP + p] = bv[i];
      cidx[(size_t)b * CAP + p] = bi[i];
    }
  }
}

// ---------- K3: sort, top-k/top-p (parallel scan), scatter, gumbel ----------
__global__ __launch_bounds__(1024) void finalize_k(
    const float* __restrict__ cvals, const int* __restrict__ cidx,
    const int* __restrict__ ccnt, const int* __restrict__ top_ks,
    const float* __restrict__ temps, const float* __restrict__ top_ps,
    float* __restrict__ out, int probs_base, int V, unsigned int half_n) {
  const int b = blockIdx.x, tid = threadIdx.x;
  __shared__ float vals[CAP];
  __shared__ int idxs[CAP];
  __shared__ float ex[1024];
  __shared__ float pr[1024];
  __shared__ float rsc[1024];
  __shared__ int rid[1024];
  __shared__ float s_S, s_S2;
  __shared__ int s_m;

  int cnt = ccnt[b];
  if (cnt > CAP) cnt = CAP;
  int k = top_ks[b];
  if (k < 1) k = 1;
  if (k > V) k = V;
  int K = (k < cnt) ? k : cnt;
  if (K > 1024) K = 1024;

  for (int i = tid; i < CAP; i += 1024) {
    if (i < cnt) { vals[i] = cvals[(size_t)b * CAP + i]; idxs[i] = cidx[(size_t)b * CAP + i]; }
    else         { vals[i] = -INFINITY;                  idxs[i] = 0x7fffffff; }
  }
  __syncthreads();

  // bitonic sort: (val desc, idx asc) == stable argsort(-logits)
  for (int size = 2; size <= CAP; size <<= 1) {
    for (int stride = size >> 1; stride > 0; stride >>= 1) {
      for (int i = tid; i < CAP; i += 1024) {
        int j = i ^ stride;
        if (j > i) {
          float vi = vals[i], vj = vals[j];
          int ii = idxs[i], ij = idxs[j];
          bool iBeforeJ = (vi > vj) || (vi == vj && ii < ij);
          bool up = ((i & size) == 0);
          if (up ? !iBeforeJ : iBeforeJ) {
            vals[i] = vj; idxs[i] = ij; vals[j] = vi; idxs[j] = ii;
          }
        }
      }
      __syncthreads();
    }
  }

  const float t = temps[b];
  const float tt = (t < 1e-5f) ? 1.0f : t;
  const float l0 = vals[0] / tt;
  for (int i = tid; i < 1024; i += 1024) {
    ex[i] = (i < K) ? expf(vals[i] / tt - l0) : 0.f;
  }
  __syncthreads();

  // S = tree-reduce(ex[0..K))
  rsc[tid] = ex[tid];
  __syncthreads();
  for (int s = 512; s > 0; s >>= 1) {
    if (tid < s) rsc[tid] += rsc[tid + s];
    __syncthreads();
  }
  if (tid == 0) s_S = rsc[0];
  __syncthreads();
  const float S = s_S;

  const float p = top_ps[b];
  int m;
  if (p >= 1.0f - 1e-5f) {
    m = K;
  } else {
    // inclusive Hillis-Steele scan of pr = ex/S (monotone since pr >= 0)
    pr[tid] = ex[tid] / S;
    __syncthreads();
    for (int off = 1; off < 1024; off <<= 1) {
      float v = pr[tid] + ((tid >= off) ? pr[tid - off] : 0.f);
      __syncthreads();
      pr[tid] = v;
      __syncthreads();
    }
    // m = max(1, #{i < K : cum[i] <= p})
    rid[tid] = (tid < K && pr[tid] <= p) ? 1 : 0;
    __syncthreads();
    for (int s = 512; s > 0; s >>= 1) {
      if (tid < s) rid[tid] += rid[tid + s];
      __syncthreads();
    }
    if (tid == 0) s_m = (rid[0] < 1) ? 1 : rid[0];
    __syncthreads();
    m = s_m;
  }
  __syncthreads();

  // S2 = tree-reduce(ex[0..m))
  rsc[tid] = (tid < m) ? ex[tid] : 0.f;
  __syncthreads();
  for (int s = 512; s > 0; s >>= 1) {
    if (tid < s) rsc[tid] += rsc[tid + s];
    __syncthreads();
  }
  if (tid == 0) s_S2 = rsc[0];
  __syncthreads();
  const float S2 = s_S2;

  for (int i = tid; i < m; i += 1024)
    out[(size_t)probs_base + (size_t)b * V + idxs[i]] = ex[i] / S2;

  float best = -INFINITY;
  int bestV = 0x7fffffff;
  for (int i = tid; i < m; i += 1024) {
    int vv = idxs[i];
    unsigned int flat = (unsigned int)b * (unsigned int)V + (unsigned int)vv;
    float g = gumbel_at(flat, half_n);
    float sc = vals[i] / tt + g;
    if (sc > best || (sc == best && vv < bestV)) { best = sc; bestV = vv; }
  }
  rsc[tid] = best; rid[tid] = bestV;
  __syncthreads();
  for (int s = 512; s > 0; s >>= 1) {
    if (tid < s) {
      float o = rsc[tid + s]; int oi = rid[tid + s];
      if (o > rsc[tid] || (o == rsc[tid] && oi < rid[tid])) { rsc[tid] = o; rid[tid] = oi; }
    }
    __syncthreads();
  }
  if (tid == 0) {
    int token = (t < 1e-5f) ? idxs[0] : rid[0];
    if (token < 0 || token >= V) token = 0;
    out[b] = (float)token;
  }
}

// ---------- launch ----------
extern "C" void kernel_launch(void* const* d_in, const int* in_sizes, int n_in,
                              void* d_out, int out_size, void* d_ws, size_t ws_size,
                              hipStream_t stream) {
  const float* hidden = (const float*)d_in[0];
  const float* emb    = (const float*)d_in[1];
  const int*   lti    = (const int*)d_in[2];
  const float* temps  = (const float*)d_in[3];
  const float* tops   = (const float*)d_in[4];
  const int*   topks  = (const int*)d_in[5];

  const int B = in_sizes[2];
  const int V = (int)(((long long)out_size - B) / B);
  const int D = in_sizes[1] / V;
  const int probs_base = out_size - B * V;  // = B
  const unsigned int half_n = (unsigned int)(((long long)B * V) / 2);

  float* out = (float*)d_out;

  char* ws = (char*)d_ws;
  size_t off = 0;
  unsigned short* Ah = (unsigned short*)(ws + off); off += (size_t)B * D * sizeof(unsigned short);
  unsigned short* Al = (unsigned short*)(ws + off); off += (size_t)B * D * sizeof(unsigned short);
  float* cvals = (float*)(ws + off); off += (size_t)B * CAP * sizeof(float);
  int* cidx = (int*)(ws + off);      off += (size_t)B * CAP * sizeof(int);
  // zeroed region: ccnt | ghist | ghist2 (contiguous, one memsetAsync)
  char* zbase = ws + off;
  int* ccnt = (int*)(ws + off);                    off += (size_t)B * sizeof(int);
  unsigned int* ghist = (unsigned int*)(ws + off); off += (size_t)B * 256 * sizeof(unsigned int);
  unsigned int* ghist2 = (unsigned int*)(ws + off); off += (size_t)B * 256 * sizeof(unsigned int);
  const size_t zbytes = (size_t)(B + B * 256 + B * 256) * sizeof(unsigned int);
  // non-zeroed scalars
  unsigned int* tau16 = (unsigned int*)(ws + off); off += (size_t)B * sizeof(unsigned int);
  int* bin_b = (int*)(ws + off);                   off += (size_t)B * sizeof(int);
  int* need_b = (int*)(ws + off);                  off += (size_t)B * sizeof(int);
  int* refine_b = (int*)(ws + off);                off += (size_t)B * sizeof(int);
  (void)ws_size; (void)n_in;

  float* logits = out + probs_base;

  hipLaunchKernelGGL(gather_split, dim3(B), dim3(256), 0, stream, hidden, lti, Ah, Al, D);
  hipMemsetAsync(zbase, 0, zbytes, stream);
  hipLaunchKernelGGL(gemm_mfma, dim3(V / BN), dim3(256), 0, stream, Ah, Al, emb, logits, D, V);
  hipLaunchKernelGGL(hist_k, dim3(8 * B), dim3(256), 0, stream, logits, ghist, V);
  hipLaunchKernelGGL(thresh1_k, dim3(B), dim3(256), 0, stream, ghist, topks, tau16, bin_b, need_b, refine_b, V);
  hipLaunchKernelGGL(refine_k, dim3(8 * B), dim3(256), 0, stream, logits, bin_b, refine_b, ghist2, V);
  hipLaunchKernelGGL(thresh2_k, dim3(B), dim3(256), 0, stream, ghist2, bin_b, need_b, refine_b, tau16);
  hipLaunchKernelGGL(gather_k, dim3(8 * B), dim3(256), 0, stream, logits, tau16, cvals, cidx, ccnt, V);
  hipLaunchKernelGGL(finalize_k, dim3(B), dim3(1024), 0, stream, cvals, cidx, ccnt,
                     topks, temps, tops, out, probs_base, V, half_n);
}

// Round 12
// 328.343 us; speedup vs baseline: 2.0168x; 1.0615x over previous
//
#include <hip/hip_runtime.h>
#include <hip/hip_bf16.h>
#include <math.h>

#define CAP 2048
#define PRNG_PARTITIONABLE 1

typedef __attribute__((ext_vector_type(8))) short bf16x8;
typedef __attribute__((ext_vector_type(4))) float f32x4;
typedef __attribute__((ext_vector_type(4))) unsigned int u32x4;

union B8U4 { u32x4 u; bf16x8 b; };

// ---------- helpers ----------
__device__ __forceinline__ unsigned int f2ord(float x) {
  unsigned int u = __float_as_uint(x);
  return (u & 0x80000000u) ? ~u : (u | 0x80000000u);
}

__device__ __forceinline__ unsigned int rotl_u32(unsigned int x, int r) {
  return (x << r) | (x >> (32 - r));
}

__device__ float gumbel_at(unsigned int flat, unsigned int half_n) {
  const unsigned int ks0 = 0u;
  const unsigned int ks1 = 42u;
  const unsigned int ks2 = 0x1BD11BDAu ^ ks0 ^ ks1;
  unsigned int x0, x1;
#if PRNG_PARTITIONABLE
  x0 = 0u;
  x1 = flat;
#else
  unsigned int cnt = (flat < half_n) ? flat : (flat - half_n);
  x0 = cnt; x1 = cnt + half_n;
#endif
  x0 += ks0; x1 += ks1;
#define TF_R(r) { x0 += x1; x1 = rotl_u32(x1, r); x1 ^= x0; }
  TF_R(13) TF_R(15) TF_R(26) TF_R(6)
  x0 += ks1; x1 += ks2 + 1u;
  TF_R(17) TF_R(29) TF_R(16) TF_R(24)
  x0 += ks2; x1 += ks0 + 2u;
  TF_R(13) TF_R(15) TF_R(26) TF_R(6)
  x0 += ks0; x1 += ks1 + 3u;
  TF_R(17) TF_R(29) TF_R(16) TF_R(24)
  x0 += ks1; x1 += ks2 + 4u;
  TF_R(13) TF_R(15) TF_R(26) TF_R(6)
  x0 += ks2; x1 += ks0 + 5u;
#undef TF_R
#if PRNG_PARTITIONABLE
  unsigned int bits = x0 ^ x1;
#else
  unsigned int bits = (flat < half_n) ? x0 : x1;
#endif
  float f = __uint_as_float(0x3f800000u | (bits >> 9)) - 1.0f;
  float u = fmaxf(1e-20f, f + 1e-20f);
  return -logf(-logf(u));
}

__device__ __forceinline__ unsigned short f32_to_bf16_rne(float x) {
  unsigned int u = __float_as_uint(x);
  unsigned int r = u + 0x7fffu + ((u >> 16) & 1u);
  return (unsigned short)(r >> 16);
}
__device__ __forceinline__ float bf16u_to_f32(unsigned short h) {
  return __uint_as_float(((unsigned int)h) << 16);
}

struct HL { unsigned int h, l; };
__device__ __forceinline__ HL cvt_pair(float a, float b) {
  float2 xf = make_float2(a, b);
  __hip_bfloat162 hh = __float22bfloat162_rn(xf);
  float2 hf = __bfloat1622float2(hh);
  __hip_bfloat162 ll = __float22bfloat162_rn(make_float2(a - hf.x, b - hf.y));
  HL r;
  __builtin_memcpy(&r.h, &hh, 4);
  __builtin_memcpy(&r.l, &ll, 4);
  return r;
}

__device__ __forceinline__ f32x4 mfma16(bf16x8 a, bf16x8 b, f32x4 c) {
  return __builtin_amdgcn_mfma_f32_16x16x32_bf16(a, b, c, 0, 0, 0);
}

// ---------- K0: gather last-token rows + split to bf16 hi/lo ----------
__global__ void gather_split(const float* __restrict__ hidden, const int* __restrict__ lti,
                             unsigned short* __restrict__ Ah, unsigned short* __restrict__ Al,
                             int D) {
  int b = blockIdx.x;
  const float* src = hidden + (size_t)lti[b] * D;
  for (int i = threadIdx.x; i < D; i += blockDim.x) {
    float x = src[i];
    unsigned short h = f32_to_bf16_rne(x);
    float r = x - bf16u_to_f32(h);
    Ah[(size_t)b * D + i] = h;
    Al[(size_t)b * D + i] = f32_to_bf16_rne(r);
  }
}

// ---------- K1: logits = A @ E^T via bf16x3 MFMA (R5 structure, 227us) ----
#define BN 128
#define BK 64
__global__ __launch_bounds__(256) void gemm_mfma(
    const unsigned short* __restrict__ Ahg, const unsigned short* __restrict__ Alg,
    const float* __restrict__ E, float* __restrict__ outL, int D, int V) {
  __shared__ __align__(16) float BS[128 * 64];
  __shared__ __align__(16) unsigned short AhS[64 * 64];
  __shared__ __align__(16) unsigned short AlS[64 * 64];

  const int t = threadIdx.x;
  const int lane = t & 63;
  const int wv = t >> 6;
  const long n0 = (long)blockIdx.x * BN;
  const int am = t >> 2, ao = t & 3;

  f32x4 acc[4][2];
#pragma unroll
  for (int i = 0; i < 4; ++i)
#pragma unroll
    for (int j = 0; j < 2; ++j) acc[i][j] = (f32x4){0.f, 0.f, 0.f, 0.f};

  f32x4 bA[8], bB[8];
  bf16x8 aA[4], aB[4];

  auto LOAD = [&](f32x4* br, bf16x8* ar, int k0) {
#pragma unroll
    for (int q = 0; q < 4; ++q) {
      int gi = q * 256 + t, n = gi >> 3, o = gi & 7;
      const float* s = E + (size_t)(n0 + n) * D + k0 + o * 8;
      br[2 * q] = *(const f32x4*)s;
      br[2 * q + 1] = *(const f32x4*)(s + 4);
    }
    const unsigned short* ph = Ahg + (size_t)am * D + k0 + ao * 16;
    ar[0] = *(const bf16x8*)ph;
    ar[1] = *(const bf16x8*)(ph + 8);
    const unsigned short* pl = Alg + (size_t)am * D + k0 + ao * 16;
    ar[2] = *(const bf16x8*)pl;
    ar[3] = *(const bf16x8*)(pl + 8);
  };

  auto STAGE = [&](f32x4* br, bf16x8* ar) {
#pragma unroll
    for (int q = 0; q < 4; ++q) {
      int gi = q * 256 + t, n = gi >> 3, o = gi & 7;
      int pg0 = (2 * o) ^ (n & 7);
      int pg1 = (2 * o + 1) ^ (n & 7);
      *(f32x4*)&BS[n * 64 + pg0 * 4] = br[2 * q];
      *(f32x4*)&BS[n * 64 + pg1 * 4] = br[2 * q + 1];
    }
    int g0 = ao * 2;
    int off0 = am * 64 + ((g0 ^ (am & 7)) * 8);
    int off1 = am * 64 + (((g0 + 1) ^ (am & 7)) * 8);
    *(bf16x8*)&AhS[off0] = ar[0];
    *(bf16x8*)&AhS[off1] = ar[1];
    *(bf16x8*)&AlS[off0] = ar[2];
    *(bf16x8*)&AlS[off1] = ar[3];
  };

  auto COMPUTE = [&]() {
#pragma unroll
    for (int k32 = 0; k32 < 2; ++k32) {
      const int og = k32 * 4 + (lane >> 4);
      bf16x8 ah[4], al[4], bh[2], bl[2];
#pragma unroll
      for (int mf = 0; mf < 4; ++mf) {
        int r = mf * 16 + (lane & 15);
        int off = r * 64 + ((og ^ (r & 7)) * 8);
        ah[mf] = *(const bf16x8*)&AhS[off];
        al[mf] = *(const bf16x8*)&AlS[off];
      }
#pragma unroll
      for (int nf = 0; nf < 2; ++nf) {
        int n = wv * 32 + nf * 16 + (lane & 15);
        int pg0 = (2 * og) ^ (n & 7);
        int pg1 = (2 * og + 1) ^ (n & 7);
        f32x4 v0 = *(const f32x4*)&BS[n * 64 + pg0 * 4];
        f32x4 v1 = *(const f32x4*)&BS[n * 64 + pg1 * 4];
        HL p0 = cvt_pair(v0.x, v0.y);
        HL p1 = cvt_pair(v0.z, v0.w);
        HL p2 = cvt_pair(v1.x, v1.y);
        HL p3 = cvt_pair(v1.z, v1.w);
        B8U4 hb, lb;
        hb.u = (u32x4){p0.h, p1.h, p2.h, p3.h};
        lb.u = (u32x4){p0.l, p1.l, p2.l, p3.l};
        bh[nf] = hb.b;
        bl[nf] = lb.b;
      }
      __builtin_amdgcn_s_setprio(1);
#pragma unroll
      for (int mf = 0; mf < 4; ++mf)
#pragma unroll
        for (int nf = 0; nf < 2; ++nf) {
          acc[mf][nf] = mfma16(ah[mf], bh[nf], acc[mf][nf]);
          acc[mf][nf] = mfma16(ah[mf], bl[nf], acc[mf][nf]);
          acc[mf][nf] = mfma16(al[mf], bh[nf], acc[mf][nf]);
        }
      __builtin_amdgcn_s_setprio(0);
    }
  };

  LOAD(bA, aA, 0);
#pragma unroll 1
  for (int k0 = 0; k0 < D; k0 += 2 * BK) {
    if (k0 + BK < D) LOAD(bB, aB, k0 + BK);
    __syncthreads();
    STAGE(bA, aA);
    __syncthreads();
    COMPUTE();
    if (k0 + 2 * BK < D) LOAD(bA, aA, k0 + 2 * BK);
    __syncthreads();
    STAGE(bB, aB);
    __syncthreads();
    COMPUTE();
  }

#pragma unroll
  for (int mf = 0; mf < 4; ++mf)
#pragma unroll
    for (int nf = 0; nf < 2; ++nf) {
      long v = n0 + wv * 32 + nf * 16 + (lane & 15);
      int rbase = mf * 16 + ((lane >> 4) << 2);
#pragma unroll
      for (int reg = 0; reg < 4; ++reg)
        outL[(size_t)(rbase + reg) * V + v] = acc[mf][nf][reg];
    }
}

// ---------- K2a: per-chunk 12-bit histogram (8 blocks/row) ----------
__global__ __launch_bounds__(256) void hist_k(
    const float* __restrict__ logits, unsigned int* __restrict__ ghist, int V) {
  const int b = blockIdx.x >> 3, c = blockIdx.x & 7;
  const int CH = V >> 3;
  const float* row = logits + (size_t)b * V;
  __shared__ unsigned int lh[4096];
  const int tid = threadIdx.x;
  for (int i = tid; i < 4096; i += 256) lh[i] = 0u;
  __syncthreads();
  const int base = c * CH;
  for (int i = base + tid * 4; i < base + CH; i += 1024) {
    f32x4 v = *(const f32x4*)(row + i);
    atomicAdd(&lh[f2ord(v.x) >> 20], 1u);
    atomicAdd(&lh[f2ord(v.y) >> 20], 1u);
    atomicAdd(&lh[f2ord(v.z) >> 20], 1u);
    atomicAdd(&lh[f2ord(v.w) >> 20], 1u);
  }
  __syncthreads();
  for (int i = tid; i < 4096; i += 256) {
    unsigned int s = lh[i];
    if (s) atomicAdd(&ghist[(size_t)b * 4096 + i], s);
  }
}

// ---------- K2b: threshold from 12-bit hist (parallel suffix scan);
//             inline rare 20-bit refine ----------
__global__ __launch_bounds__(1024) void thresh_k(
    const float* __restrict__ logits, const unsigned int* __restrict__ ghist,
    const int* __restrict__ top_ks, unsigned int* __restrict__ tau20, int V) {
  const int b = blockIdx.x, tid = threadIdx.x;
  __shared__ unsigned int h[4096];
  __shared__ unsigned int ts[1024];
  __shared__ unsigned int h2[256];
  __shared__ int s_bin, s_cntGT, s_found;

  // load histogram row
  for (int i = tid; i < 4096; i += 1024) h[i] = ghist[(size_t)b * 4096 + i];
  if (tid == 0) s_found = 0;
  __syncthreads();

  int k = top_ks[b];
  if (k < 1) k = 1;
  if (k > V) k = V;
  const unsigned int uk = (unsigned int)k;

  // per-thread segment sum (bins [4t, 4t+4))
  unsigned int s0 = h[4 * tid] + h[4 * tid + 1] + h[4 * tid + 2] + h[4 * tid + 3];
  ts[tid] = s0;
  __syncthreads();
  // inclusive suffix scan over thread segments
  for (int off = 1; off < 1024; off <<= 1) {
    unsigned int v = ts[tid] + ((tid + off < 1024) ? ts[tid + off] : 0u);
    __syncthreads();
    ts[tid] = v;
    __syncthreads();
  }
  // count strictly above my segment
  unsigned int above = ts[tid] - s0;
  // unique crossing: run goes from above (<k?) to above+s0 (>=k?)
  if (above < uk && above + s0 >= uk) {
    unsigned int run = above;
    for (int j = 3; j >= 0; --j) {
      unsigned int hj = h[4 * tid + j];
      if (run < uk && run + hj >= uk) {
        s_bin = 4 * tid + j;
        s_cntGT = (int)run;
        s_found = 1;
        break;
      }
      run += hj;
    }
  }
  __syncthreads();
  int bin = s_found ? s_bin : 0;
  int cntGT = s_found ? s_cntGT : 0;

  // common case: whole boundary bin fits in CAP
  if (cntGT + (int)h[bin] <= CAP) {
    if (tid == 0) tau20[b] = ((unsigned int)bin) << 8;
    return;
  }

  // rare: refine by next 8 bits within boundary bin (full row scan)
  for (int i = tid; i < 256; i += 1024) h2[i] = 0u;
  __syncthreads();
  const float* row = logits + (size_t)b * V;
  const unsigned int binq = (unsigned int)bin;
  for (int i = tid * 4; i < V; i += 4096) {
    f32x4 v = *(const f32x4*)(row + i);
#pragma unroll
    for (int e = 0; e < 4; ++e) {
      unsigned int u = f2ord(v[e]);
      if ((u >> 20) == binq) atomicAdd(&h2[(u >> 12) & 255u], 1u);
    }
  }
  __syncthreads();
  if (tid == 0) {
    int need = k - cntGT;  // >= 1
    unsigned int run = 0;
    int sub = 255;
    for (; sub >= 0; --sub) {
      unsigned int hh = h2[sub];
      if (run + hh >= (unsigned int)need) break;
      run += hh;
    }
    if (sub < 0) sub = 0;
    tau20[b] = (binq << 8) | (unsigned int)sub;
  }
}

// ---------- K2c: gather candidates (20-bit compare) + zero chunk ----------
__global__ __launch_bounds__(256) void gather_k(
    float* __restrict__ logits, const unsigned int* __restrict__ tau20,
    float* __restrict__ cvals, int* __restrict__ cidx, int* __restrict__ ccnt, int V) {
  const int b = blockIdx.x >> 3, c = blockIdx.x & 7;
  const int CH = V >> 3;
  float* row = logits + (size_t)b * V;
  __shared__ float bv[CAP];
  __shared__ int bi[CAP];
  __shared__ int s_c, s_base;
  const int tid = threadIdx.x;
  if (tid == 0) s_c = 0;
  __syncthreads();
  const unsigned int tau = tau20[b];
  const int base = c * CH;
  const f32x4 z = (f32x4){0.f, 0.f, 0.f, 0.f};
  for (int i = base + tid * 4; i < base + CH; i += 1024) {
    f32x4 v = *(const f32x4*)(row + i);
#pragma unroll
    for (int e = 0; e < 4; ++e) {
      float x = v[e];
      if ((f2ord(x) >> 12) >= tau) {
        int p = atomicAdd(&s_c, 1);
        if (p < CAP) { bv[p] = x; bi[p] = i + e; }
      }
    }
    *(f32x4*)(row + i) = z;
  }
  __syncthreads();
  int cnt = s_c;
  if (cnt > CAP) cnt = CAP;
  if (tid == 0) s_base = atomicAdd(ccnt + b, cnt);
  __syncthreads();
  const int gb = s_base;
  for (int i = tid; i < cnt; i += 256) {
    int p = gb + i;
    if (p < CAP) {
      cvals[(size_t)b * CAP + p] = bv[i];
      cidx[(size_t)b * CAP + p] = bi[i];
    }
  }
}

// ---------- K3: sort, top-k/top-p (parallel scan), scatter, gumbel ----------
__global__ __launch_bounds__(1024) void finalize_k(
    const float* __restrict__ cvals, const int* __restrict__ cidx,
    const int* __restrict__ ccnt, const int* __restrict__ top_ks,
    const float* __restrict__ temps, const float* __restrict__ top_ps,
    float* __restrict__ out, int probs_base, int V, unsigned int half_n) {
  const int b = blockIdx.x, tid = threadIdx.x;
  __shared__ float vals[CAP];
  __shared__ int idxs[CAP];
  __shared__ float ex[1024];
  __shared__ float pr[1024];
  __shared__ float rsc[1024];
  __shared__ int rid[1024];
  __shared__ float s_S, s_S2;
  __shared__ int s_m;

  int cnt = ccnt[b];
  if (cnt > CAP) cnt = CAP;
  int k = top_ks[b];
  if (k < 1) k = 1;
  if (k > V) k = V;
  int K = (k < cnt) ? k : cnt;
  if (K > 1024) K = 1024;

  for (int i = tid; i < CAP; i += 1024) {
    if (i < cnt) { vals[i] = cvals[(size_t)b * CAP + i]; idxs[i] = cidx[(size_t)b * CAP + i]; }
    else         { vals[i] = -INFINITY;                  idxs[i] = 0x7fffffff; }
  }
  __syncthreads();

  // bitonic sort: (val desc, idx asc) == stable argsort(-logits)
  for (int size = 2; size <= CAP; size <<= 1) {
    for (int stride = size >> 1; stride > 0; stride >>= 1) {
      for (int i = tid; i < CAP; i += 1024) {
        int j = i ^ stride;
        if (j > i) {
          float vi = vals[i], vj = vals[j];
          int ii = idxs[i], ij = idxs[j];
          bool iBeforeJ = (vi > vj) || (vi == vj && ii < ij);
          bool up = ((i & size) == 0);
          if (up ? !iBeforeJ : iBeforeJ) {
            vals[i] = vj; idxs[i] = ij; vals[j] = vi; idxs[j] = ii;
          }
        }
      }
      __syncthreads();
    }
  }

  const float t = temps[b];
  const float tt = (t < 1e-5f) ? 1.0f : t;
  const float l0 = vals[0] / tt;
  ex[tid] = (tid < K) ? expf(vals[tid] / tt - l0) : 0.f;
  __syncthreads();

  // S = tree-reduce(ex[0..K))
  rsc[tid] = ex[tid];
  __syncthreads();
  for (int s = 512; s > 0; s >>= 1) {
    if (tid < s) rsc[tid] += rsc[tid + s];
    __syncthreads();
  }
  if (tid == 0) s_S = rsc[0];
  __syncthreads();
  const float S = s_S;

  const float p = top_ps[b];
  int m;
  if (p >= 1.0f - 1e-5f) {
    m = K;
  } else {
    pr[tid] = ex[tid] / S;
    __syncthreads();
    for (int off = 1; off < 1024; off <<= 1) {
      float v = pr[tid] + ((tid >= off) ? pr[tid - off] : 0.f);
      __syncthreads();
      pr[tid] = v;
      __syncthreads();
    }
    rid[tid] = (tid < K && pr[tid] <= p) ? 1 : 0;
    __syncthreads();
    for (int s = 512; s > 0; s >>= 1) {
      if (tid < s) rid[tid] += rid[tid + s];
      __syncthreads();
    }
    if (tid == 0) s_m = (rid[0] < 1) ? 1 : rid[0];
    __syncthreads();
    m = s_m;
  }
  __syncthreads();

  // S2 = tree-reduce(ex[0..m))
  rsc[tid] = (tid < m) ? ex[tid] : 0.f;
  __syncthreads();
  for (int s = 512; s > 0; s >>= 1) {
    if (tid < s) rsc[tid] += rsc[tid + s];
    __syncthreads();
  }
  if (tid == 0) s_S2 = rsc[0];
  __syncthreads();
  const float S2 = s_S2;

  for (int i = tid; i < m; i += 1024)
    out[(size_t)probs_base + (size_t)b * V + idxs[i]] = ex[i] / S2;

  float best = -INFINITY;
  int bestV = 0x7fffffff;
  for (int i = tid; i < m; i += 1024) {
    int vv = idxs[i];
    unsigned int flat = (unsigned int)b * (unsigned int)V + (unsigned int)vv;
    float g = gumbel_at(flat, half_n);
    float sc = vals[i] / tt + g;
    if (sc > best || (sc == best && vv < bestV)) { best = sc; bestV = vv; }
  }
  rsc[tid] = best; rid[tid] = bestV;
  __syncthreads();
  for (int s = 512; s > 0; s >>= 1) {
    if (tid < s) {
      float o = rsc[tid + s]; int oi = rid[tid + s];
      if (o > rsc[tid] || (o == rsc[tid] && oi < rid[tid])) { rsc[tid] = o; rid[tid] = oi; }
    }
    __syncthreads();
  }
  if (tid == 0) {
    int token = (t < 1e-5f) ? idxs[0] : rid[0];
    if (token < 0 || token >= V) token = 0;
    out[b] = (float)token;
  }
}

// ---------- launch ----------
extern "C" void kernel_launch(void* const* d_in, const int* in_sizes, int n_in,
                              void* d_out, int out_size, void* d_ws, size_t ws_size,
                              hipStream_t stream) {
  const float* hidden = (const float*)d_in[0];
  const float* emb    = (const float*)d_in[1];
  const int*   lti    = (const int*)d_in[2];
  const float* temps  = (const float*)d_in[3];
  const float* tops   = (const float*)d_in[4];
  const int*   topks  = (const int*)d_in[5];

  const int B = in_sizes[2];
  const int V = (int)(((long long)out_size - B) / B);
  const int D = in_sizes[1] / V;
  const int probs_base = out_size - B * V;  // = B
  const unsigned int half_n = (unsigned int)(((long long)B * V) / 2);

  float* out = (float*)d_out;

  char* ws = (char*)d_ws;
  size_t off = 0;
  unsigned short* Ah = (unsigned short*)(ws + off); off += (size_t)B * D * sizeof(unsigned short);
  unsigned short* Al = (unsigned short*)(ws + off); off += (size_t)B * D * sizeof(unsigned short);
  float* cvals = (float*)(ws + off); off += (size_t)B * CAP * sizeof(float);
  int* cidx = (int*)(ws + off);      off += (size_t)B * CAP * sizeof(int);
  // zeroed region: ccnt | ghist(4096 bins/row) — one memsetAsync
  char* zbase = ws + off;
  int* ccnt = (int*)(ws + off);                    off += (size_t)B * sizeof(int);
  unsigned int* ghist = (unsigned int*)(ws + off); off += (size_t)B * 4096 * sizeof(unsigned int);
  const size_t zbytes = (size_t)(B + B * 4096) * sizeof(unsigned int);
  unsigned int* tau20 = (unsigned int*)(ws + off); off += (size_t)B * sizeof(unsigned int);
  (void)ws_size; (void)n_in;

  float* logits = out + probs_base;

  hipLaunchKernelGGL(gather_split, dim3(B), dim3(256), 0, stream, hidden, lti, Ah, Al, D);
  hipMemsetAsync(zbase, 0, zbytes, stream);
  hipLaunchKernelGGL(gemm_mfma, dim3(V / BN), dim3(256), 0, stream, Ah, Al, emb, logits, D, V);
  hipLaunchKernelGGL(hist_k, dim3(8 * B), dim3(256), 0, stream, logits, ghist, V);
  hipLaunchKernelGGL(thresh_k, dim3(B), dim3(1024), 0, stream, logits, ghist, topks, tau20, V);
  hipLaunchKernelGGL(gather_k, dim3(8 * B), dim3(256), 0, stream, logits, tau20, cvals, cidx, ccnt, V);
  hipLaunchKernelGGL(finalize_k, dim3(B), dim3(1024), 0, stream, cvals, cidx, ccnt,
                     topks, temps, tops, out, probs_base, V, half_n);
}